// Round 6
// baseline (1381.174 us; speedup 1.0000x reference)
//
#include <hip/hip_runtime.h>
#include <hip/hip_bf16.h>

// ---------------- problem constants ----------------
#define NN 100000      // nodes
#define NE 1600000     // edges (before self-loops)
#define ET 1700000     // edges + self-loops
#define NG 64          // graphs
#define F_IN 128
#define HID 64         // 4 heads * 16
#define NLAYERS 6      // hidden GAT layers (plus input layer)
#define NEG 0.2f
#define NB_SCAN ((NN + 1023) / 1024)   // 98
#define NPART 8        // dst partitions (XCD heuristic)
#define PBLK 128       // blocks per partition
#define PNN (NN / NPART)   // 12500

static __device__ __forceinline__ unsigned short f2bf(float f) {
    __hip_bfloat16 b = __float2bfloat16(f);
    return *reinterpret_cast<unsigned short*>(&b);
}
static __device__ __forceinline__ float bf2f(unsigned short u) {
    __hip_bfloat16 b = *reinterpret_cast<__hip_bfloat16*>(&u);
    return __bfloat162float(b);
}

// ---------------- CSR build (dst-partitioned for XCD L2 locality) ----------------
__global__ __launch_bounds__(256) void k_hist(const int* __restrict__ ei,
                                              int* __restrict__ counts) {
    const int part = blockIdx.x & (NPART - 1);
    const int sub  = blockIdx.x >> 3;
    const int lo = part * PNN, hi = lo + PNN;
    for (int e = sub * 256 + threadIdx.x; e < ET; e += PBLK * 256) {
        int dst = (e < NE) ? ei[NE + e] : (e - NE);
        if (dst >= lo && dst < hi) atomicAdd(&counts[dst], 1);
    }
}

__global__ void k_scan_blocks(const int* __restrict__ counts,
                              int* __restrict__ excl, int* __restrict__ bsums) {
    __shared__ int sh[256];
    int b = blockIdx.x, t = threadIdx.x;
    int base = b * 1024 + t * 4;
    int c[4];
    #pragma unroll
    for (int j = 0; j < 4; ++j) {
        int idx = base + j;
        c[j] = (idx < NN) ? counts[idx] : 0;
    }
    int s = c[0] + c[1] + c[2] + c[3];
    sh[t] = s;
    __syncthreads();
    for (int off = 1; off < 256; off <<= 1) {
        int v = (t >= off) ? sh[t - off] : 0;
        __syncthreads();
        sh[t] += v;
        __syncthreads();
    }
    int run = sh[t] - s;
    #pragma unroll
    for (int j = 0; j < 4; ++j) {
        int idx = base + j;
        if (idx < NN) excl[idx] = run;
        run += c[j];
    }
    if (t == 255) bsums[b] = sh[t];
}

__global__ void k_scan_partials(const int* __restrict__ bsums, int* __restrict__ boffs) {
    if (threadIdx.x == 0 && blockIdx.x == 0) {
        int run = 0;
        for (int i = 0; i < NB_SCAN; ++i) { boffs[i] = run; run += bsums[i]; }
    }
}

__global__ void k_add_offsets(int* __restrict__ rowptr, const int* __restrict__ boffs,
                              int* __restrict__ cursor) {
    int idx = blockIdx.x * blockDim.x + threadIdx.x;
    if (idx < NN) {
        int v = rowptr[idx] + boffs[blockIdx.x];
        rowptr[idx] = v;
        cursor[idx] = v;
    }
    if (idx == 0) rowptr[NN] = ET;
}

__global__ __launch_bounds__(256) void k_scatter(const int* __restrict__ ei,
                                                 int* __restrict__ cursor,
                                                 int* __restrict__ csr_src) {
    const int part = blockIdx.x & (NPART - 1);
    const int sub  = blockIdx.x >> 3;
    const int lo = part * PNN, hi = lo + PNN;
    for (int e = sub * 256 + threadIdx.x; e < ET; e += PBLK * 256) {
        int dst = (e < NE) ? ei[NE + e] : (e - NE);
        if (dst >= lo && dst < hi) {
            int src = (e < NE) ? ei[e] : dst;
            int pos = atomicAdd(&cursor[dst], 1);
            csr_src[pos] = src;
        }
    }
}

// ---------------- GEMM (h @ W) fused with alpha reductions ----------------
// hw output is bf16 (message values); alphas stay f32.
template<int F>
__global__ __launch_bounds__(256) void k_gemm_alpha(
    const float* __restrict__ hin,   // [NN, F]
    const float* __restrict__ W,     // [F, 64]
    const float* __restrict__ asrc,  // [4,16]
    const float* __restrict__ adst,  // [4,16]
    unsigned short* __restrict__ hw, // [NN, 64] bf16
    float* __restrict__ as_,         // [NN, 4]
    float* __restrict__ ad_)         // [NN, 4]
{
    __shared__ float hs[64][65];
    __shared__ float Ws[64][64];
    const int t = threadIdx.x;
    const int n0 = blockIdx.x * 64;
    const int tc = t & 15;
    const int tn = t >> 4;

    float acc[4][4] = {};

    for (int kt = 0; kt < F; kt += 64) {
        __syncthreads();
        #pragma unroll
        for (int i = t; i < 4096; i += 256) {
            int n = i >> 6, k = i & 63;
            int gn = n0 + n;
            hs[n][k] = (gn < NN) ? hin[(size_t)gn * F + kt + k] : 0.f;
            Ws[n][k] = W[(size_t)(kt + n) * 64 + k];
        }
        __syncthreads();
        #pragma unroll
        for (int k = 0; k < 64; ++k) {
            const float4 bv = *reinterpret_cast<const float4*>(&Ws[k][tc * 4]);
            float a0 = hs[tn * 4 + 0][k];
            float a1 = hs[tn * 4 + 1][k];
            float a2 = hs[tn * 4 + 2][k];
            float a3 = hs[tn * 4 + 3][k];
            acc[0][0] += a0 * bv.x; acc[0][1] += a0 * bv.y; acc[0][2] += a0 * bv.z; acc[0][3] += a0 * bv.w;
            acc[1][0] += a1 * bv.x; acc[1][1] += a1 * bv.y; acc[1][2] += a1 * bv.z; acc[1][3] += a1 * bv.w;
            acc[2][0] += a2 * bv.x; acc[2][1] += a2 * bv.y; acc[2][2] += a2 * bv.z; acc[2][3] += a2 * bv.w;
            acc[3][0] += a3 * bv.x; acc[3][1] += a3 * bv.y; acc[3][2] += a3 * bv.z; acc[3][3] += a3 * bv.w;
        }
    }

    const int head = tc >> 2;
    #pragma unroll
    for (int i = 0; i < 4; ++i) {
        int n = n0 + tn * 4 + i;
        if (n < NN) {
            ushort4 v;
            v.x = f2bf(acc[i][0]);
            v.y = f2bf(acc[i][1]);
            v.z = f2bf(acc[i][2]);
            v.w = f2bf(acc[i][3]);
            *reinterpret_cast<ushort4*>(&hw[(size_t)n * 64 + tc * 4]) = v;
        }
        float vs = 0.f, vd = 0.f;
        #pragma unroll
        for (int j = 0; j < 4; ++j) {
            int c = (tc * 4 + j) & 15;
            vs += acc[i][j] * asrc[head * 16 + c];
            vd += acc[i][j] * adst[head * 16 + c];
        }
        vs += __shfl_xor(vs, 1); vs += __shfl_xor(vs, 2);
        vd += __shfl_xor(vd, 1); vd += __shfl_xor(vd, 2);
        if ((tc & 3) == 0 && n < NN) {
            as_[n * 4 + head] = vs;
            ad_[n * 4 + head] = vd;
        }
    }
}

// ---------------- fused two-phase aggregation (bf16 hw gather) ----------------
__global__ __launch_bounds__(256) void k_aggregate(
    const unsigned short* __restrict__ hw, // [NN,64] bf16
    const float* __restrict__ as_,     // [NN,4]
    const float* __restrict__ ad_,     // [NN,4]
    const int* __restrict__ rowptr,
    const int* __restrict__ csr_src,
    const float* __restrict__ bias,    // [64]
    float* __restrict__ out)           // [NN,64]
{
    int wave = (blockIdx.x * blockDim.x + threadIdx.x) >> 6;
    int lane = threadIdx.x & 63;
    if (wave >= NN) return;
    const int n = wave;
    const int beg = rowptr[n], end = rowptr[n + 1];

    // ---- phase 1: per-head (m, l) ----
    const int h1 = lane & 3;
    const int slot = lane >> 2;
    const float adn1 = ad_[n * 4 + h1];
    float m = -1e30f, l = 0.f;
    for (int i = beg + slot; i < end; i += 16) {
        int s = csr_src[i];
        float e = as_[s * 4 + h1] + adn1;
        e = (e > 0.f) ? e : NEG * e;
        float mn = fmaxf(m, e);
        l = l * __expf(m - mn) + __expf(e - mn);
        m = mn;
    }
    #pragma unroll
    for (int off = 4; off < 64; off <<= 1) {
        float m2 = __shfl_xor(m, off);
        float l2 = __shfl_xor(l, off);
        float mn = fmaxf(m, m2);
        l = l * __expf(m - mn) + l2 * __expf(m2 - mn);
        m = mn;
    }
    const int h2 = lane >> 4;
    const float mh = __shfl(m, h2);
    const float lh = __shfl(l, h2);

    // ---- phase 2: independent weighted gather, 4 in flight ----
    const float adn = ad_[n * 4 + h2];
    const float inv_l = 1.f / (lh + 1e-16f);
    float acc = 0.f;
    int i = beg;
    for (; i + 4 <= end; i += 4) {
        int s0 = csr_src[i + 0];
        int s1 = csr_src[i + 1];
        int s2 = csr_src[i + 2];
        int s3 = csr_src[i + 3];
        float e0 = as_[s0 * 4 + h2] + adn;
        float e1 = as_[s1 * 4 + h2] + adn;
        float e2 = as_[s2 * 4 + h2] + adn;
        float e3 = as_[s3 * 4 + h2] + adn;
        e0 = (e0 > 0.f) ? e0 : NEG * e0;
        e1 = (e1 > 0.f) ? e1 : NEG * e1;
        e2 = (e2 > 0.f) ? e2 : NEG * e2;
        e3 = (e3 > 0.f) ? e3 : NEG * e3;
        float p0 = __expf(e0 - mh);
        float p1 = __expf(e1 - mh);
        float p2 = __expf(e2 - mh);
        float p3 = __expf(e3 - mh);
        unsigned short u0 = hw[(size_t)s0 * 64 + lane];
        unsigned short u1 = hw[(size_t)s1 * 64 + lane];
        unsigned short u2 = hw[(size_t)s2 * 64 + lane];
        unsigned short u3 = hw[(size_t)s3 * 64 + lane];
        acc += p0 * bf2f(u0) + p1 * bf2f(u1) + p2 * bf2f(u2) + p3 * bf2f(u3);
    }
    for (; i < end; ++i) {
        int s = csr_src[i];
        float e = as_[s * 4 + h2] + adn;
        e = (e > 0.f) ? e : NEG * e;
        float p = __expf(e - mh);
        acc += p * bf2f(hw[(size_t)s * 64 + lane]);
    }
    float o = acc * inv_l + bias[lane];
    out[(size_t)n * 64 + lane] = (o > 0.f) ? o : 0.f;
}

// ---------------- global max pool (batch sorted, h >= 0) ----------------
__global__ void k_pool(const float* __restrict__ h, const int* __restrict__ batch,
                       unsigned int* __restrict__ g) {
    int wave = (blockIdx.x * blockDim.x + threadIdx.x) >> 6;
    int lane = threadIdx.x & 63;
    int n0 = wave * 32;
    if (n0 >= NN) return;
    int n1 = n0 + 32; if (n1 > NN) n1 = NN;
    int cg = batch[n0];
    float m = 0.f;
    for (int n = n0; n < n1; ++n) {
        int gi = batch[n];
        if (gi != cg) {
            atomicMax(&g[cg * 64 + lane], __float_as_uint(m));
            m = 0.f; cg = gi;
        }
        m = fmaxf(m, h[(size_t)n * 64 + lane]);
    }
    atomicMax(&g[cg * 64 + lane], __float_as_uint(m));
}

// ---------------- MLP head ----------------
__global__ void k_head(const unsigned int* __restrict__ gbits,
                       const float* __restrict__ W1, const float* __restrict__ b1,
                       const float* __restrict__ W2, const float* __restrict__ b2,
                       float* __restrict__ out) {
    __shared__ float gs[NG * 64];
    __shared__ float z1[NG * 32];
    int t = threadIdx.x;
    for (int i = t; i < NG * 64; i += 256) gs[i] = __uint_as_float(gbits[i]);
    __syncthreads();
    for (int i = t; i < NG * 32; i += 256) {
        int gi = i >> 5, c = i & 31;
        float acc = b1[c];
        for (int k = 0; k < 64; ++k) acc += gs[gi * 64 + k] * W1[k * 32 + c];
        z1[i] = (acc > 0.f) ? acc : 0.f;
    }
    __syncthreads();
    for (int i = t; i < NG * 10; i += 256) {
        int gi = i / 10, c = i % 10;
        float acc = b2[c];
        for (int k = 0; k < 32; ++k) acc += z1[gi * 32 + k] * W2[k * 10 + c];
        out[i] = acc;
    }
}

// ---------------- launch ----------------
extern "C" void kernel_launch(void* const* d_in, const int* in_sizes, int n_in,
                              void* d_out, int out_size, void* d_ws, size_t ws_size,
                              hipStream_t stream) {
    const float* x       = (const float*)d_in[0];
    const int*   ei      = (const int*)d_in[1];
    const int*   batch   = (const int*)d_in[2];
    const float* W_in    = (const float*)d_in[3];
    const float* asrc_in = (const float*)d_in[4];
    const float* adst_in = (const float*)d_in[5];
    const float* b_in    = (const float*)d_in[6];
    const float* W_hid   = (const float*)d_in[7];
    const float* asrc_h  = (const float*)d_in[8];
    const float* adst_h  = (const float*)d_in[9];
    const float* b_hid   = (const float*)d_in[10];
    const float* W1      = (const float*)d_in[11];
    const float* b1      = (const float*)d_in[12];
    const float* W2      = (const float*)d_in[13];
    const float* b2      = (const float*)d_in[14];
    float* out = (float*)d_out;

    char* base = (char*)d_ws;
    size_t off = 0;
    auto alloc = [&](size_t bytes) -> char* {
        char* p = base + off;
        off += (bytes + 255) & ~size_t(255);
        return p;
    };
    float* A      = (float*)alloc((size_t)NN * 64 * 4);
    unsigned short* Bf = (unsigned short*)alloc((size_t)NN * 64 * 2);  // bf16 hw
    float* as_    = (float*)alloc((size_t)NN * 4 * 4);
    float* ad_    = (float*)alloc((size_t)NN * 4 * 4);
    int*   counts = (int*)alloc((size_t)NN * 4);
    int*   rowptr = (int*)alloc((size_t)(NN + 1) * 4);
    int*   cursor = (int*)alloc((size_t)(NN + 1) * 4);
    int*   bsums  = (int*)alloc((size_t)NB_SCAN * 4);
    int*   boffs  = (int*)alloc((size_t)NB_SCAN * 4);
    int*   csr    = (int*)alloc((size_t)ET * 4);
    unsigned int* g = (unsigned int*)alloc((size_t)NG * 64 * 4);

    hipMemsetAsync(counts, 0, (size_t)NN * 4, stream);
    hipMemsetAsync(g, 0, (size_t)NG * 64 * 4, stream);

    k_hist<<<NPART * PBLK, 256, 0, stream>>>(ei, counts);
    k_scan_blocks<<<NB_SCAN, 256, 0, stream>>>(counts, rowptr, bsums);
    k_scan_partials<<<1, 64, 0, stream>>>(bsums, boffs);
    k_add_offsets<<<NB_SCAN, 1024, 0, stream>>>(rowptr, boffs, cursor);
    k_scatter<<<NPART * PBLK, 256, 0, stream>>>(ei, cursor, csr);

    const int gemm_blocks = (NN + 63) / 64;
    const int agg_blocks  = (NN * 64 + 255) / 256;

    // input layer: F=128
    k_gemm_alpha<128><<<gemm_blocks, 256, 0, stream>>>(x, W_in, asrc_in, adst_in, Bf, as_, ad_);
    k_aggregate<<<agg_blocks, 256, 0, stream>>>(Bf, as_, ad_, rowptr, csr, b_in, A);

    // hidden layers: F=64
    for (int i = 0; i < NLAYERS; ++i) {
        k_gemm_alpha<64><<<gemm_blocks, 256, 0, stream>>>(
            A, W_hid + (size_t)i * 64 * 64, asrc_h + (size_t)i * 64, adst_h + (size_t)i * 64,
            Bf, as_, ad_);
        k_aggregate<<<agg_blocks, 256, 0, stream>>>(Bf, as_, ad_, rowptr, csr, b_hid + (size_t)i * 64, A);
    }

    int pool_waves = (NN + 31) / 32;
    int pool_blocks = (pool_waves * 64 + 255) / 256;
    k_pool<<<pool_blocks, 256, 0, stream>>>(A, batch, g);
    k_head<<<1, 256, 0, stream>>>(g, W1, b1, W2, b2, out);
}

// Round 7
// 1187.036 us; speedup vs baseline: 1.1635x; 1.1635x over previous
//
#include <hip/hip_runtime.h>
#include <hip/hip_bf16.h>

// ---------------- problem constants ----------------
#define NN 100000      // nodes
#define NE 1600000     // edges (before self-loops)
#define ET 1700000     // edges + self-loops
#define NG 64          // graphs
#define F_IN 128
#define HID 64         // 4 heads * 16
#define NLAYERS 6      // hidden GAT layers (plus input layer)
#define NEG 0.2f
#define NB_SCAN ((NN + 1023) / 1024)   // 98
#define NPART 8        // dst partitions (XCD heuristic)
#define PBLK 128       // blocks per partition
#define PNN (NN / NPART)   // 12500

static __device__ __forceinline__ unsigned short f2bf(float f) {
    __hip_bfloat16 b = __float2bfloat16(f);
    return *reinterpret_cast<unsigned short*>(&b);
}
static __device__ __forceinline__ float bf2f(unsigned short u) {
    __hip_bfloat16 b = *reinterpret_cast<__hip_bfloat16*>(&u);
    return __bfloat162float(b);
}

// ---------------- CSR build (dst-partitioned for XCD L2 locality) ----------------
__global__ __launch_bounds__(256) void k_hist(const int* __restrict__ ei,
                                              int* __restrict__ counts) {
    const int part = blockIdx.x & (NPART - 1);
    const int sub  = blockIdx.x >> 3;
    const int lo = part * PNN, hi = lo + PNN;
    for (int e = sub * 256 + threadIdx.x; e < ET; e += PBLK * 256) {
        int dst = (e < NE) ? ei[NE + e] : (e - NE);
        if (dst >= lo && dst < hi) atomicAdd(&counts[dst], 1);
    }
}

__global__ void k_scan_blocks(const int* __restrict__ counts,
                              int* __restrict__ excl, int* __restrict__ bsums) {
    __shared__ int sh[256];
    int b = blockIdx.x, t = threadIdx.x;
    int base = b * 1024 + t * 4;
    int c[4];
    #pragma unroll
    for (int j = 0; j < 4; ++j) {
        int idx = base + j;
        c[j] = (idx < NN) ? counts[idx] : 0;
    }
    int s = c[0] + c[1] + c[2] + c[3];
    sh[t] = s;
    __syncthreads();
    for (int off = 1; off < 256; off <<= 1) {
        int v = (t >= off) ? sh[t - off] : 0;
        __syncthreads();
        sh[t] += v;
        __syncthreads();
    }
    int run = sh[t] - s;
    #pragma unroll
    for (int j = 0; j < 4; ++j) {
        int idx = base + j;
        if (idx < NN) excl[idx] = run;
        run += c[j];
    }
    if (t == 255) bsums[b] = sh[t];
}

__global__ void k_scan_partials(const int* __restrict__ bsums, int* __restrict__ boffs) {
    if (threadIdx.x == 0 && blockIdx.x == 0) {
        int run = 0;
        for (int i = 0; i < NB_SCAN; ++i) { boffs[i] = run; run += bsums[i]; }
    }
}

__global__ void k_add_offsets(int* __restrict__ rowptr, const int* __restrict__ boffs,
                              int* __restrict__ cursor) {
    int idx = blockIdx.x * blockDim.x + threadIdx.x;
    if (idx < NN) {
        int v = rowptr[idx] + boffs[blockIdx.x];
        rowptr[idx] = v;
        cursor[idx] = v;
    }
    if (idx == 0) rowptr[NN] = ET;
}

__global__ __launch_bounds__(256) void k_scatter(const int* __restrict__ ei,
                                                 int* __restrict__ cursor,
                                                 int* __restrict__ csr_src) {
    const int part = blockIdx.x & (NPART - 1);
    const int sub  = blockIdx.x >> 3;
    const int lo = part * PNN, hi = lo + PNN;
    for (int e = sub * 256 + threadIdx.x; e < ET; e += PBLK * 256) {
        int dst = (e < NE) ? ei[NE + e] : (e - NE);
        if (dst >= lo && dst < hi) {
            int src = (e < NE) ? ei[e] : dst;
            int pos = atomicAdd(&cursor[dst], 1);
            csr_src[pos] = src;
        }
    }
}

// ---------------- lean GEMM (h @ W) fused with alpha reductions ----------------
// 32 nodes x 64 cols per block (NN % 32 == 0: no bounds checks), K-chunk 32,
// 2x4 micro-tile -> low VGPR, 12.4 KB LDS, full occupancy.
template<int F>
__global__ __launch_bounds__(256) void k_gemm_alpha(
    const float* __restrict__ hin,   // [NN, F]
    const float* __restrict__ W,     // [F, 64]
    const float* __restrict__ asrc,  // [4,16]
    const float* __restrict__ adst,  // [4,16]
    unsigned short* __restrict__ hw, // [NN, 64] bf16
    float* __restrict__ as_,         // [NN, 4]
    float* __restrict__ ad_)         // [NN, 4]
{
    __shared__ float hs[32][33];     // padded
    __shared__ float Ws[32][64];
    const int t = threadIdx.x;
    const int n0 = blockIdx.x * 32;
    const int tc = t & 15;           // col quad: cols tc*4..tc*4+3
    const int tn = t >> 4;           // node pair: nodes tn*2, tn*2+1

    float acc[2][4] = {};

    for (int kt = 0; kt < F; kt += 32) {
        __syncthreads();
        {
            int row = t >> 3, c4 = t & 7;   // 32 rows x 8 float4
            float4 v = *reinterpret_cast<const float4*>(&hin[(size_t)(n0 + row) * F + kt + c4 * 4]);
            hs[row][c4 * 4 + 0] = v.x;
            hs[row][c4 * 4 + 1] = v.y;
            hs[row][c4 * 4 + 2] = v.z;
            hs[row][c4 * 4 + 3] = v.w;
            #pragma unroll
            for (int u = 0; u < 2; ++u) {
                int idx = t + u * 256;
                int r = idx >> 4, c = idx & 15;
                *reinterpret_cast<float4*>(&Ws[r][c * 4]) =
                    *reinterpret_cast<const float4*>(&W[(size_t)(kt + r) * 64 + c * 4]);
            }
        }
        __syncthreads();
        #pragma unroll
        for (int k = 0; k < 32; ++k) {
            const float4 bv = *reinterpret_cast<const float4*>(&Ws[k][tc * 4]);
            float a0 = hs[tn * 2 + 0][k];
            float a1 = hs[tn * 2 + 1][k];
            acc[0][0] += a0 * bv.x; acc[0][1] += a0 * bv.y; acc[0][2] += a0 * bv.z; acc[0][3] += a0 * bv.w;
            acc[1][0] += a1 * bv.x; acc[1][1] += a1 * bv.y; acc[1][2] += a1 * bv.z; acc[1][3] += a1 * bv.w;
        }
    }

    const int head = tc >> 2;
    #pragma unroll
    for (int i = 0; i < 2; ++i) {
        int n = n0 + tn * 2 + i;
        ushort4 v;
        v.x = f2bf(acc[i][0]);
        v.y = f2bf(acc[i][1]);
        v.z = f2bf(acc[i][2]);
        v.w = f2bf(acc[i][3]);
        *reinterpret_cast<ushort4*>(&hw[(size_t)n * 64 + tc * 4]) = v;

        float vs = 0.f, vd = 0.f;
        #pragma unroll
        for (int j = 0; j < 4; ++j) {
            int c = (tc * 4 + j) & 15;
            vs += acc[i][j] * asrc[head * 16 + c];
            vd += acc[i][j] * adst[head * 16 + c];
        }
        vs += __shfl_xor(vs, 1); vs += __shfl_xor(vs, 2);
        vd += __shfl_xor(vd, 1); vd += __shfl_xor(vd, 2);
        if ((tc & 3) == 0) {
            as_[n * 4 + head] = vs;
            ad_[n * 4 + head] = vd;
        }
    }
}

// ---------------- per-node softmax -> normalized bf16 edge weights ----------------
// one wave per node; lane = (slot 0..15) x (head 0..3). Phase A is the
// byte-identical proven (m,l) online reduction; phase B writes
// p_hat = exp(e - m) / l to pn (coalesced 128B stores: index is lane-linear).
__global__ __launch_bounds__(256) void k_edge_softmax(
    const float* __restrict__ as_,     // [NN,4]
    const float* __restrict__ ad_,     // [NN,4]
    const int* __restrict__ rowptr,
    const int* __restrict__ csr_src,
    unsigned short* __restrict__ pn)   // [ET,4] bf16
{
    int wave = (blockIdx.x * blockDim.x + threadIdx.x) >> 6;
    int lane = threadIdx.x & 63;
    if (wave >= NN) return;
    const int n = wave;
    const int beg = rowptr[n], end = rowptr[n + 1];
    const int deg = end - beg;
    const int h1 = lane & 3;
    const int slot = lane >> 2;
    const float adn1 = ad_[n * 4 + h1];

    float m = -1e30f, l = 0.f;
    for (int j = slot; j < deg; j += 16) {
        int s = csr_src[beg + j];
        float e = as_[s * 4 + h1] + adn1;
        e = (e > 0.f) ? e : NEG * e;
        float mn = fmaxf(m, e);
        l = l * __expf(m - mn) + __expf(e - mn);
        m = mn;
    }
    #pragma unroll
    for (int off = 4; off < 64; off <<= 1) {
        float m2 = __shfl_xor(m, off);
        float l2 = __shfl_xor(l, off);
        float mn = fmaxf(m, m2);
        l = l * __expf(m - mn) + l2 * __expf(m2 - mn);
        m = mn;
    }
    const float inv_l = 1.f / (l + 1e-16f);

    for (int j = slot; j < deg; j += 16) {
        int s = csr_src[beg + j];
        float e = as_[s * 4 + h1] + adn1;
        e = (e > 0.f) ? e : NEG * e;
        pn[(size_t)(beg + j) * 4 + h1] = f2bf(__expf(e - m) * inv_l);
    }
}

// ---------------- lean aggregation: out[n] = sum p_hat * hw[src] ----------------
__global__ __launch_bounds__(256) void k_aggregate(
    const unsigned short* __restrict__ hw, // [NN,64] bf16
    const unsigned short* __restrict__ pn, // [ET,4] bf16
    const int* __restrict__ rowptr,
    const int* __restrict__ csr_src,
    const float* __restrict__ bias,    // [64]
    float* __restrict__ out)           // [NN,64]
{
    int wave = (blockIdx.x * blockDim.x + threadIdx.x) >> 6;
    int lane = threadIdx.x & 63;
    if (wave >= NN) return;
    const int n = wave;
    const int beg = rowptr[n], end = rowptr[n + 1];
    const int h2 = lane >> 4;

    float acc = 0.f;
    int i = beg;
    for (; i + 4 <= end; i += 4) {
        int s0 = csr_src[i + 0];
        int s1 = csr_src[i + 1];
        int s2 = csr_src[i + 2];
        int s3 = csr_src[i + 3];
        float p0 = bf2f(pn[(size_t)(i + 0) * 4 + h2]);
        float p1 = bf2f(pn[(size_t)(i + 1) * 4 + h2]);
        float p2 = bf2f(pn[(size_t)(i + 2) * 4 + h2]);
        float p3 = bf2f(pn[(size_t)(i + 3) * 4 + h2]);
        float v0 = bf2f(hw[(size_t)s0 * 64 + lane]);
        float v1 = bf2f(hw[(size_t)s1 * 64 + lane]);
        float v2 = bf2f(hw[(size_t)s2 * 64 + lane]);
        float v3 = bf2f(hw[(size_t)s3 * 64 + lane]);
        acc += p0 * v0 + p1 * v1 + p2 * v2 + p3 * v3;
    }
    for (; i < end; ++i) {
        int s = csr_src[i];
        float p = bf2f(pn[(size_t)i * 4 + h2]);
        acc += p * bf2f(hw[(size_t)s * 64 + lane]);
    }
    float o = acc + bias[lane];
    out[(size_t)n * 64 + lane] = (o > 0.f) ? o : 0.f;
}

// ---------------- global max pool (batch sorted, h >= 0) ----------------
__global__ void k_pool(const float* __restrict__ h, const int* __restrict__ batch,
                       unsigned int* __restrict__ g) {
    int wave = (blockIdx.x * blockDim.x + threadIdx.x) >> 6;
    int lane = threadIdx.x & 63;
    int n0 = wave * 32;
    if (n0 >= NN) return;
    int n1 = n0 + 32; if (n1 > NN) n1 = NN;
    int cg = batch[n0];
    float m = 0.f;
    for (int n = n0; n < n1; ++n) {
        int gi = batch[n];
        if (gi != cg) {
            atomicMax(&g[cg * 64 + lane], __float_as_uint(m));
            m = 0.f; cg = gi;
        }
        m = fmaxf(m, h[(size_t)n * 64 + lane]);
    }
    atomicMax(&g[cg * 64 + lane], __float_as_uint(m));
}

// ---------------- MLP head ----------------
__global__ void k_head(const unsigned int* __restrict__ gbits,
                       const float* __restrict__ W1, const float* __restrict__ b1,
                       const float* __restrict__ W2, const float* __restrict__ b2,
                       float* __restrict__ out) {
    __shared__ float gs[NG * 64];
    __shared__ float z1[NG * 32];
    int t = threadIdx.x;
    for (int i = t; i < NG * 64; i += 256) gs[i] = __uint_as_float(gbits[i]);
    __syncthreads();
    for (int i = t; i < NG * 32; i += 256) {
        int gi = i >> 5, c = i & 31;
        float acc = b1[c];
        for (int k = 0; k < 64; ++k) acc += gs[gi * 64 + k] * W1[k * 32 + c];
        z1[i] = (acc > 0.f) ? acc : 0.f;
    }
    __syncthreads();
    for (int i = t; i < NG * 10; i += 256) {
        int gi = i / 10, c = i % 10;
        float acc = b2[c];
        for (int k = 0; k < 32; ++k) acc += z1[gi * 32 + k] * W2[k * 10 + c];
        out[i] = acc;
    }
}

// ---------------- launch ----------------
extern "C" void kernel_launch(void* const* d_in, const int* in_sizes, int n_in,
                              void* d_out, int out_size, void* d_ws, size_t ws_size,
                              hipStream_t stream) {
    const float* x       = (const float*)d_in[0];
    const int*   ei      = (const int*)d_in[1];
    const int*   batch   = (const int*)d_in[2];
    const float* W_in    = (const float*)d_in[3];
    const float* asrc_in = (const float*)d_in[4];
    const float* adst_in = (const float*)d_in[5];
    const float* b_in    = (const float*)d_in[6];
    const float* W_hid   = (const float*)d_in[7];
    const float* asrc_h  = (const float*)d_in[8];
    const float* adst_h  = (const float*)d_in[9];
    const float* b_hid   = (const float*)d_in[10];
    const float* W1      = (const float*)d_in[11];
    const float* b1      = (const float*)d_in[12];
    const float* W2      = (const float*)d_in[13];
    const float* b2      = (const float*)d_in[14];
    float* out = (float*)d_out;

    char* base = (char*)d_ws;
    size_t off = 0;
    auto alloc = [&](size_t bytes) -> char* {
        char* p = base + off;
        off += (bytes + 255) & ~size_t(255);
        return p;
    };
    float* A      = (float*)alloc((size_t)NN * 64 * 4);
    unsigned short* Bf = (unsigned short*)alloc((size_t)NN * 64 * 2);  // bf16 hw
    unsigned short* pn = (unsigned short*)alloc((size_t)ET * 4 * 2);   // bf16 p_hat
    float* as_    = (float*)alloc((size_t)NN * 4 * 4);
    float* ad_    = (float*)alloc((size_t)NN * 4 * 4);
    int*   counts = (int*)alloc((size_t)NN * 4);
    int*   rowptr = (int*)alloc((size_t)(NN + 1) * 4);
    int*   cursor = (int*)alloc((size_t)(NN + 1) * 4);
    int*   bsums  = (int*)alloc((size_t)NB_SCAN * 4);
    int*   boffs  = (int*)alloc((size_t)NB_SCAN * 4);
    int*   csr    = (int*)alloc((size_t)ET * 4);
    unsigned int* g = (unsigned int*)alloc((size_t)NG * 64 * 4);

    hipMemsetAsync(counts, 0, (size_t)NN * 4, stream);
    hipMemsetAsync(g, 0, (size_t)NG * 64 * 4, stream);

    k_hist<<<NPART * PBLK, 256, 0, stream>>>(ei, counts);
    k_scan_blocks<<<NB_SCAN, 256, 0, stream>>>(counts, rowptr, bsums);
    k_scan_partials<<<1, 64, 0, stream>>>(bsums, boffs);
    k_add_offsets<<<NB_SCAN, 1024, 0, stream>>>(rowptr, boffs, cursor);
    k_scatter<<<NPART * PBLK, 256, 0, stream>>>(ei, cursor, csr);

    const int gemm_blocks = NN / 32;                    // exact
    const int node_blocks = (NN * 64 + 255) / 256;      // one wave per node

    // input layer: F=128
    k_gemm_alpha<128><<<gemm_blocks, 256, 0, stream>>>(x, W_in, asrc_in, adst_in, Bf, as_, ad_);
    k_edge_softmax<<<node_blocks, 256, 0, stream>>>(as_, ad_, rowptr, csr, pn);
    k_aggregate<<<node_blocks, 256, 0, stream>>>(Bf, pn, rowptr, csr, b_in, A);

    // hidden layers: F=64
    for (int i = 0; i < NLAYERS; ++i) {
        k_gemm_alpha<64><<<gemm_blocks, 256, 0, stream>>>(
            A, W_hid + (size_t)i * 64 * 64, asrc_h + (size_t)i * 64, adst_h + (size_t)i * 64,
            Bf, as_, ad_);
        k_edge_softmax<<<node_blocks, 256, 0, stream>>>(as_, ad_, rowptr, csr, pn);
        k_aggregate<<<node_blocks, 256, 0, stream>>>(Bf, pn, rowptr, csr, b_hid + (size_t)i * 64, A);
    }

    int pool_waves = (NN + 31) / 32;
    int pool_blocks = (pool_waves * 64 + 255) / 256;
    k_pool<<<pool_blocks, 256, 0, stream>>>(A, batch, g);
    k_head<<<1, 256, 0, stream>>>(g, W1, b1, W2, b2, out);
}

// Round 8
// 948.249 us; speedup vs baseline: 1.4566x; 1.2518x over previous
//
#include <hip/hip_runtime.h>
#include <hip/hip_bf16.h>

// ---------------- problem constants ----------------
#define NN 100000      // nodes
#define NE 1600000     // edges (before self-loops)
#define ET 1700000     // edges + self-loops
#define NG 64          // graphs
#define F_IN 128
#define HID 64         // 4 heads * 16
#define NLAYERS 6      // hidden GAT layers (plus input layer)
#define NEG 0.2f
#define NB_SCAN ((NN + 1023) / 1024)   // 98
#define NPART 8        // dst partitions (XCD heuristic)
#define PBLK 128       // blocks per partition
#define PNN (NN / NPART)   // 12500
#define DCAP 64        // per-wave LDS edge capacity (deg ~ Poisson(16)+1)

static __device__ __forceinline__ unsigned short f2bf(float f) {
    __hip_bfloat16 b = __float2bfloat16(f);
    return *reinterpret_cast<unsigned short*>(&b);
}
static __device__ __forceinline__ float bf2f(unsigned short u) {
    __hip_bfloat16 b = *reinterpret_cast<__hip_bfloat16*>(&u);
    return __bfloat162float(b);
}

// ---------------- CSR build (dst-partitioned for XCD L2 locality) ----------------
__global__ __launch_bounds__(256) void k_hist(const int* __restrict__ ei,
                                              int* __restrict__ counts) {
    const int part = blockIdx.x & (NPART - 1);
    const int sub  = blockIdx.x >> 3;
    const int lo = part * PNN, hi = lo + PNN;
    for (int e = sub * 256 + threadIdx.x; e < ET; e += PBLK * 256) {
        int dst = (e < NE) ? ei[NE + e] : (e - NE);
        if (dst >= lo && dst < hi) atomicAdd(&counts[dst], 1);
    }
}

__global__ void k_scan_blocks(const int* __restrict__ counts,
                              int* __restrict__ excl, int* __restrict__ bsums) {
    __shared__ int sh[256];
    int b = blockIdx.x, t = threadIdx.x;
    int base = b * 1024 + t * 4;
    int c[4];
    #pragma unroll
    for (int j = 0; j < 4; ++j) {
        int idx = base + j;
        c[j] = (idx < NN) ? counts[idx] : 0;
    }
    int s = c[0] + c[1] + c[2] + c[3];
    sh[t] = s;
    __syncthreads();
    for (int off = 1; off < 256; off <<= 1) {
        int v = (t >= off) ? sh[t - off] : 0;
        __syncthreads();
        sh[t] += v;
        __syncthreads();
    }
    int run = sh[t] - s;
    #pragma unroll
    for (int j = 0; j < 4; ++j) {
        int idx = base + j;
        if (idx < NN) excl[idx] = run;
        run += c[j];
    }
    if (t == 255) bsums[b] = sh[t];
}

__global__ void k_scan_partials(const int* __restrict__ bsums, int* __restrict__ boffs) {
    if (threadIdx.x == 0 && blockIdx.x == 0) {
        int run = 0;
        for (int i = 0; i < NB_SCAN; ++i) { boffs[i] = run; run += bsums[i]; }
    }
}

__global__ void k_add_offsets(int* __restrict__ rowptr, const int* __restrict__ boffs,
                              int* __restrict__ cursor) {
    int idx = blockIdx.x * blockDim.x + threadIdx.x;
    if (idx < NN) {
        int v = rowptr[idx] + boffs[blockIdx.x];
        rowptr[idx] = v;
        cursor[idx] = v;
    }
    if (idx == 0) rowptr[NN] = ET;
}

__global__ __launch_bounds__(256) void k_scatter(const int* __restrict__ ei,
                                                 int* __restrict__ cursor,
                                                 int* __restrict__ csr_src) {
    const int part = blockIdx.x & (NPART - 1);
    const int sub  = blockIdx.x >> 3;
    const int lo = part * PNN, hi = lo + PNN;
    for (int e = sub * 256 + threadIdx.x; e < ET; e += PBLK * 256) {
        int dst = (e < NE) ? ei[NE + e] : (e - NE);
        if (dst >= lo && dst < hi) {
            int src = (e < NE) ? ei[e] : dst;
            int pos = atomicAdd(&cursor[dst], 1);
            csr_src[pos] = src;
        }
    }
}

// ---------------- lean GEMM (h @ W) fused with alpha reductions ----------------
// 32 nodes x 64 cols per block, K-chunk 32, 2x4 micro-tile.
// BIN: input activations are bf16 (hidden layers); else f32 (input layer).
template<int F, bool BIN>
__global__ __launch_bounds__(256) void k_gemm_alpha(
    const void* __restrict__ hin_,   // [NN, F] f32 or bf16
    const float* __restrict__ W,     // [F, 64]
    const float* __restrict__ asrc,  // [4,16]
    const float* __restrict__ adst,  // [4,16]
    unsigned short* __restrict__ hw, // [NN, 64] bf16
    float* __restrict__ as_,         // [NN, 4]
    float* __restrict__ ad_)         // [NN, 4]
{
    __shared__ float hs[32][33];     // padded
    __shared__ float Ws[32][64];
    const int t = threadIdx.x;
    const int n0 = blockIdx.x * 32;
    const int tc = t & 15;           // col quad: cols tc*4..tc*4+3
    const int tn = t >> 4;           // node pair: nodes tn*2, tn*2+1

    float acc[2][4] = {};

    for (int kt = 0; kt < F; kt += 32) {
        __syncthreads();
        {
            int row = t >> 3, q = t & 7;   // 32 rows x 8 quads
            if constexpr (BIN) {
                const unsigned short* hb = (const unsigned short*)hin_;
                ushort4 u = *reinterpret_cast<const ushort4*>(&hb[(size_t)(n0 + row) * F + kt + q * 4]);
                hs[row][q * 4 + 0] = bf2f(u.x);
                hs[row][q * 4 + 1] = bf2f(u.y);
                hs[row][q * 4 + 2] = bf2f(u.z);
                hs[row][q * 4 + 3] = bf2f(u.w);
            } else {
                const float* hf = (const float*)hin_;
                float4 v = *reinterpret_cast<const float4*>(&hf[(size_t)(n0 + row) * F + kt + q * 4]);
                hs[row][q * 4 + 0] = v.x;
                hs[row][q * 4 + 1] = v.y;
                hs[row][q * 4 + 2] = v.z;
                hs[row][q * 4 + 3] = v.w;
            }
            #pragma unroll
            for (int u = 0; u < 2; ++u) {
                int idx = t + u * 256;
                int r = idx >> 4, c = idx & 15;
                *reinterpret_cast<float4*>(&Ws[r][c * 4]) =
                    *reinterpret_cast<const float4*>(&W[(size_t)(kt + r) * 64 + c * 4]);
            }
        }
        __syncthreads();
        #pragma unroll
        for (int k = 0; k < 32; ++k) {
            const float4 bv = *reinterpret_cast<const float4*>(&Ws[k][tc * 4]);
            float a0 = hs[tn * 2 + 0][k];
            float a1 = hs[tn * 2 + 1][k];
            acc[0][0] += a0 * bv.x; acc[0][1] += a0 * bv.y; acc[0][2] += a0 * bv.z; acc[0][3] += a0 * bv.w;
            acc[1][0] += a1 * bv.x; acc[1][1] += a1 * bv.y; acc[1][2] += a1 * bv.z; acc[1][3] += a1 * bv.w;
        }
    }

    const int head = tc >> 2;
    #pragma unroll
    for (int i = 0; i < 2; ++i) {
        int n = n0 + tn * 2 + i;
        ushort4 v;
        v.x = f2bf(acc[i][0]);
        v.y = f2bf(acc[i][1]);
        v.z = f2bf(acc[i][2]);
        v.w = f2bf(acc[i][3]);
        *reinterpret_cast<ushort4*>(&hw[(size_t)n * 64 + tc * 4]) = v;

        float vs = 0.f, vd = 0.f;
        #pragma unroll
        for (int j = 0; j < 4; ++j) {
            int c = (tc * 4 + j) & 15;
            vs += acc[i][j] * asrc[head * 16 + c];
            vd += acc[i][j] * adst[head * 16 + c];
        }
        vs += __shfl_xor(vs, 1); vs += __shfl_xor(vs, 2);
        vd += __shfl_xor(vd, 1); vd += __shfl_xor(vd, 2);
        if ((tc & 3) == 0) {
            as_[n * 4 + head] = vs;
            ad_[n * 4 + head] = vd;
        }
    }
}

// ---------------- fused softmax + aggregation (LDS-staged p, s) ----------------
// one wave per node. Phase 1: proven online (m,l) over (slot,head) lanes,
// stashing e (f32) and src into per-wave LDS. Phase 2: normalize p in LDS.
// Phase 3: weighted hw gather with p/s broadcast from LDS.
__global__ __launch_bounds__(256) void k_aggregate(
    const unsigned short* __restrict__ hw, // [NN,64] bf16
    const float* __restrict__ as_,     // [NN,4]
    const float* __restrict__ ad_,     // [NN,4]
    const int* __restrict__ rowptr,
    const int* __restrict__ csr_src,
    const float* __restrict__ bias,    // [64]
    unsigned short* __restrict__ outA) // [NN,64] bf16
{
    __shared__ float pls[4][DCAP][4];
    __shared__ int   sls[4][DCAP];
    const int wv = threadIdx.x >> 6;
    int wave = (blockIdx.x * blockDim.x + threadIdx.x) >> 6;
    int lane = threadIdx.x & 63;
    if (wave >= NN) return;
    const int n = wave;
    const int beg = rowptr[n], end = rowptr[n + 1];
    const int deg = end - beg;
    const int h1 = lane & 3;
    const int slot = lane >> 2;
    const float adn1 = ad_[n * 4 + h1];

    // ---- phase 1: online (m,l); stash e and src ----
    float m = -1e30f, l = 0.f;
    for (int j = slot; j < deg; j += 16) {
        int s = csr_src[beg + j];
        float e = as_[s * 4 + h1] + adn1;
        e = (e > 0.f) ? e : NEG * e;
        if (j < DCAP) {
            if (h1 == 0) sls[wv][j] = s;
            pls[wv][j][h1] = e;
        }
        float mn = fmaxf(m, e);
        l = l * __expf(m - mn) + __expf(e - mn);
        m = mn;
    }
    #pragma unroll
    for (int off = 4; off < 64; off <<= 1) {
        float m2 = __shfl_xor(m, off);
        float l2 = __shfl_xor(l, off);
        float mn = fmaxf(m, m2);
        l = l * __expf(m - mn) + l2 * __expf(m2 - mn);
        m = mn;
    }
    const float inv_l = 1.f / (l + 1e-16f);

    // ---- phase 2: normalize p in LDS (per-lane linear addresses) ----
    const int dcap = (deg < DCAP) ? deg : DCAP;
    for (int j = slot; j < dcap; j += 16)
        pls[wv][j][h1] = __expf(pls[wv][j][h1] - m) * inv_l;

    // ---- phase 3: weighted gather ----
    const int h2 = lane >> 4;
    const float mh2 = __shfl(m, h2);       // head h2's max (rare fallback)
    const float il2 = __shfl(inv_l, h2);
    float acc = 0.f;
    int i = 0;
    for (; i + 4 <= dcap; i += 4) {
        int s0 = sls[wv][i + 0];
        int s1 = sls[wv][i + 1];
        int s2 = sls[wv][i + 2];
        int s3 = sls[wv][i + 3];
        float p0 = pls[wv][i + 0][h2];
        float p1 = pls[wv][i + 1][h2];
        float p2 = pls[wv][i + 2][h2];
        float p3 = pls[wv][i + 3][h2];
        float v0 = bf2f(hw[(size_t)s0 * 64 + lane]);
        float v1 = bf2f(hw[(size_t)s1 * 64 + lane]);
        float v2 = bf2f(hw[(size_t)s2 * 64 + lane]);
        float v3 = bf2f(hw[(size_t)s3 * 64 + lane]);
        acc += p0 * v0 + p1 * v1 + p2 * v2 + p3 * v3;
    }
    for (; i < dcap; ++i) {
        int s = sls[wv][i];
        acc += pls[wv][i][h2] * bf2f(hw[(size_t)s * 64 + lane]);
    }
    if (deg > DCAP) {
        const float adn2 = ad_[n * 4 + h2];
        for (; i < deg; ++i) {
            int s = csr_src[beg + i];
            float e = as_[s * 4 + h2] + adn2;
            e = (e > 0.f) ? e : NEG * e;
            acc += __expf(e - mh2) * il2 * bf2f(hw[(size_t)s * 64 + lane]);
        }
    }
    float o = acc + bias[lane];
    outA[(size_t)n * 64 + lane] = f2bf((o > 0.f) ? o : 0.f);
}

// ---------------- global max pool (batch sorted, h >= 0) ----------------
__global__ void k_pool(const unsigned short* __restrict__ h, const int* __restrict__ batch,
                       unsigned int* __restrict__ g) {
    int wave = (blockIdx.x * blockDim.x + threadIdx.x) >> 6;
    int lane = threadIdx.x & 63;
    int n0 = wave * 32;
    if (n0 >= NN) return;
    int n1 = n0 + 32; if (n1 > NN) n1 = NN;
    int cg = batch[n0];
    float m = 0.f;
    for (int n = n0; n < n1; ++n) {
        int gi = batch[n];
        if (gi != cg) {
            atomicMax(&g[cg * 64 + lane], __float_as_uint(m));
            m = 0.f; cg = gi;
        }
        m = fmaxf(m, bf2f(h[(size_t)n * 64 + lane]));
    }
    atomicMax(&g[cg * 64 + lane], __float_as_uint(m));
}

// ---------------- MLP head ----------------
__global__ void k_head(const unsigned int* __restrict__ gbits,
                       const float* __restrict__ W1, const float* __restrict__ b1,
                       const float* __restrict__ W2, const float* __restrict__ b2,
                       float* __restrict__ out) {
    __shared__ float gs[NG * 64];
    __shared__ float z1[NG * 32];
    int t = threadIdx.x;
    for (int i = t; i < NG * 64; i += 256) gs[i] = __uint_as_float(gbits[i]);
    __syncthreads();
    for (int i = t; i < NG * 32; i += 256) {
        int gi = i >> 5, c = i & 31;
        float acc = b1[c];
        for (int k = 0; k < 64; ++k) acc += gs[gi * 64 + k] * W1[k * 32 + c];
        z1[i] = (acc > 0.f) ? acc : 0.f;
    }
    __syncthreads();
    for (int i = t; i < NG * 10; i += 256) {
        int gi = i / 10, c = i % 10;
        float acc = b2[c];
        for (int k = 0; k < 32; ++k) acc += z1[gi * 32 + k] * W2[k * 10 + c];
        out[i] = acc;
    }
}

// ---------------- launch ----------------
extern "C" void kernel_launch(void* const* d_in, const int* in_sizes, int n_in,
                              void* d_out, int out_size, void* d_ws, size_t ws_size,
                              hipStream_t stream) {
    const float* x       = (const float*)d_in[0];
    const int*   ei      = (const int*)d_in[1];
    const int*   batch   = (const int*)d_in[2];
    const float* W_in    = (const float*)d_in[3];
    const float* asrc_in = (const float*)d_in[4];
    const float* adst_in = (const float*)d_in[5];
    const float* b_in    = (const float*)d_in[6];
    const float* W_hid   = (const float*)d_in[7];
    const float* asrc_h  = (const float*)d_in[8];
    const float* adst_h  = (const float*)d_in[9];
    const float* b_hid   = (const float*)d_in[10];
    const float* W1      = (const float*)d_in[11];
    const float* b1      = (const float*)d_in[12];
    const float* W2      = (const float*)d_in[13];
    const float* b2      = (const float*)d_in[14];
    float* out = (float*)d_out;

    char* base = (char*)d_ws;
    size_t off = 0;
    auto alloc = [&](size_t bytes) -> char* {
        char* p = base + off;
        off += (bytes + 255) & ~size_t(255);
        return p;
    };
    unsigned short* A  = (unsigned short*)alloc((size_t)NN * 64 * 2);  // bf16 activations
    unsigned short* Bf = (unsigned short*)alloc((size_t)NN * 64 * 2);  // bf16 hw messages
    float* as_    = (float*)alloc((size_t)NN * 4 * 4);
    float* ad_    = (float*)alloc((size_t)NN * 4 * 4);
    int*   counts = (int*)alloc((size_t)NN * 4);
    int*   rowptr = (int*)alloc((size_t)(NN + 1) * 4);
    int*   cursor = (int*)alloc((size_t)(NN + 1) * 4);
    int*   bsums  = (int*)alloc((size_t)NB_SCAN * 4);
    int*   boffs  = (int*)alloc((size_t)NB_SCAN * 4);
    int*   csr    = (int*)alloc((size_t)ET * 4);
    unsigned int* g = (unsigned int*)alloc((size_t)NG * 64 * 4);

    hipMemsetAsync(counts, 0, (size_t)NN * 4, stream);
    hipMemsetAsync(g, 0, (size_t)NG * 64 * 4, stream);

    k_hist<<<NPART * PBLK, 256, 0, stream>>>(ei, counts);
    k_scan_blocks<<<NB_SCAN, 256, 0, stream>>>(counts, rowptr, bsums);
    k_scan_partials<<<1, 64, 0, stream>>>(bsums, boffs);
    k_add_offsets<<<NB_SCAN, 1024, 0, stream>>>(rowptr, boffs, cursor);
    k_scatter<<<NPART * PBLK, 256, 0, stream>>>(ei, cursor, csr);

    const int gemm_blocks = NN / 32;                    // exact
    const int node_blocks = (NN * 64 + 255) / 256;      // one wave per node

    // input layer: F=128, f32 input
    k_gemm_alpha<128, false><<<gemm_blocks, 256, 0, stream>>>(x, W_in, asrc_in, adst_in, Bf, as_, ad_);
    k_aggregate<<<node_blocks, 256, 0, stream>>>(Bf, as_, ad_, rowptr, csr, b_in, A);

    // hidden layers: F=64, bf16 input
    for (int i = 0; i < NLAYERS; ++i) {
        k_gemm_alpha<64, true><<<gemm_blocks, 256, 0, stream>>>(
            A, W_hid + (size_t)i * 64 * 64, asrc_h + (size_t)i * 64, adst_h + (size_t)i * 64,
            Bf, as_, ad_);
        k_aggregate<<<node_blocks, 256, 0, stream>>>(Bf, as_, ad_, rowptr, csr, b_hid + (size_t)i * 64, A);
    }

    int pool_waves = (NN + 31) / 32;
    int pool_blocks = (pool_waves * 64 + 255) / 256;
    k_pool<<<pool_blocks, 256, 0, stream>>>(A, batch, g);
    k_head<<<1, 256, 0, stream>>>(g, W1, b1, W2, b2, out);
}

// Round 9
// 790.409 us; speedup vs baseline: 1.7474x; 1.1997x over previous
//
#include <hip/hip_runtime.h>
#include <hip/hip_bf16.h>

// ---------------- problem constants ----------------
#define NN 100000      // nodes
#define NE 1600000     // edges (before self-loops)
#define ET 1700000     // edges + self-loops
#define NG 64          // graphs
#define F_IN 128
#define HID 64         // 4 heads * 16
#define NLAYERS 6      // hidden GAT layers (plus input layer)
#define NEG 0.2f
#define NB_SCAN ((NN + 1023) / 1024)   // 98
#define NPART 8        // dst partitions (XCD heuristic)
#define PBLK 128       // blocks per partition
#define PNN (NN / NPART)   // 12500
#define DCAP 64        // per-wave LDS edge capacity (deg ~ Poisson(16)+1)

static __device__ __forceinline__ unsigned short f2bf(float f) {
    __hip_bfloat16 b = __float2bfloat16(f);
    return *reinterpret_cast<unsigned short*>(&b);
}
static __device__ __forceinline__ float bf2f(unsigned short u) {
    __hip_bfloat16 b = *reinterpret_cast<__hip_bfloat16*>(&u);
    return __bfloat162float(b);
}

// ---------------- CSR build (dst-partitioned for XCD L2 locality) ----------------
__global__ __launch_bounds__(256) void k_hist(const int* __restrict__ ei,
                                              int* __restrict__ counts) {
    const int part = blockIdx.x & (NPART - 1);
    const int sub  = blockIdx.x >> 3;
    const int lo = part * PNN, hi = lo + PNN;
    for (int e = sub * 256 + threadIdx.x; e < ET; e += PBLK * 256) {
        int dst = (e < NE) ? ei[NE + e] : (e - NE);
        if (dst >= lo && dst < hi) atomicAdd(&counts[dst], 1);
    }
}

__global__ void k_scan_blocks(const int* __restrict__ counts,
                              int* __restrict__ excl, int* __restrict__ bsums) {
    __shared__ int sh[256];
    int b = blockIdx.x, t = threadIdx.x;
    int base = b * 1024 + t * 4;
    int c[4];
    #pragma unroll
    for (int j = 0; j < 4; ++j) {
        int idx = base + j;
        c[j] = (idx < NN) ? counts[idx] : 0;
    }
    int s = c[0] + c[1] + c[2] + c[3];
    sh[t] = s;
    __syncthreads();
    for (int off = 1; off < 256; off <<= 1) {
        int v = (t >= off) ? sh[t - off] : 0;
        __syncthreads();
        sh[t] += v;
        __syncthreads();
    }
    int run = sh[t] - s;
    #pragma unroll
    for (int j = 0; j < 4; ++j) {
        int idx = base + j;
        if (idx < NN) excl[idx] = run;
        run += c[j];
    }
    if (t == 255) bsums[b] = sh[t];
}

__global__ void k_scan_partials(const int* __restrict__ bsums, int* __restrict__ boffs) {
    if (threadIdx.x == 0 && blockIdx.x == 0) {
        int run = 0;
        for (int i = 0; i < NB_SCAN; ++i) { boffs[i] = run; run += bsums[i]; }
    }
}

__global__ void k_add_offsets(int* __restrict__ rowptr, const int* __restrict__ boffs,
                              int* __restrict__ cursor) {
    int idx = blockIdx.x * blockDim.x + threadIdx.x;
    if (idx < NN) {
        int v = rowptr[idx] + boffs[blockIdx.x];
        rowptr[idx] = v;
        cursor[idx] = v;
    }
    if (idx == 0) rowptr[NN] = ET;
}

__global__ __launch_bounds__(256) void k_scatter(const int* __restrict__ ei,
                                                 int* __restrict__ cursor,
                                                 int* __restrict__ csr_src) {
    const int part = blockIdx.x & (NPART - 1);
    const int sub  = blockIdx.x >> 3;
    const int lo = part * PNN, hi = lo + PNN;
    for (int e = sub * 256 + threadIdx.x; e < ET; e += PBLK * 256) {
        int dst = (e < NE) ? ei[NE + e] : (e - NE);
        if (dst >= lo && dst < hi) {
            int src = (e < NE) ? ei[e] : dst;
            int pos = atomicAdd(&cursor[dst], 1);
            csr_src[pos] = src;
        }
    }
}

// ---------------- GEMM (h @ W) fused with alpha reductions ----------------
// Tile 64 nodes x 64 cols, K-chunk 32, 4x4 micro-tile.
// hs row-major [64][36] (scalar a-reads: 4 addrs/wave, 2 banks -> free);
// Ws [32][64] (b128 b-reads, stride 256B: aligned, 2-way -> free).
// BIN: input activations bf16 (hidden layers); else f32 (input layer).
template<int F, bool BIN>
__global__ __launch_bounds__(256) void k_gemm_alpha(
    const void* __restrict__ hin_,   // [NN, F] f32 or bf16
    const float* __restrict__ W,     // [F, 64]
    const float* __restrict__ asrc,  // [4,16]
    const float* __restrict__ adst,  // [4,16]
    unsigned short* __restrict__ hw, // [NN, 64] bf16
    float* __restrict__ as_,         // [NN, 4]
    float* __restrict__ ad_)         // [NN, 4]
{
    __shared__ float hs[64][36];     // [node][k], K-chunk 32 + pad
    __shared__ float Ws[32][64];     // [k][col]
    const int t = threadIdx.x;
    const int n0 = blockIdx.x * 64;
    const int tc = t & 15;           // col quad: cols tc*4..tc*4+3
    const int tn = t >> 4;           // node quad: nodes tn*4..tn*4+3

    float acc[4][4] = {};

    for (int kt = 0; kt < F; kt += 32) {
        __syncthreads();
        // stage A: 64 rows x 8 quads = 512 quads, 2 per thread
        #pragma unroll
        for (int u = 0; u < 2; ++u) {
            int idx = t + u * 256;
            int row = idx >> 3, q = idx & 7;
            int gn = n0 + row;
            if constexpr (BIN) {
                const unsigned short* hb = (const unsigned short*)hin_;
                ushort4 uv = (gn < NN)
                    ? *reinterpret_cast<const ushort4*>(&hb[(size_t)gn * F + kt + q * 4])
                    : make_ushort4(0, 0, 0, 0);
                hs[row][q * 4 + 0] = bf2f(uv.x);
                hs[row][q * 4 + 1] = bf2f(uv.y);
                hs[row][q * 4 + 2] = bf2f(uv.z);
                hs[row][q * 4 + 3] = bf2f(uv.w);
            } else {
                const float* hf = (const float*)hin_;
                float4 v = (gn < NN)
                    ? *reinterpret_cast<const float4*>(&hf[(size_t)gn * F + kt + q * 4])
                    : make_float4(0.f, 0.f, 0.f, 0.f);
                hs[row][q * 4 + 0] = v.x;
                hs[row][q * 4 + 1] = v.y;
                hs[row][q * 4 + 2] = v.z;
                hs[row][q * 4 + 3] = v.w;
            }
        }
        // stage B: 32 rows x 16 quads = 512 quads, 2 per thread
        #pragma unroll
        for (int u = 0; u < 2; ++u) {
            int idx = t + u * 256;
            int r = idx >> 4, c = idx & 15;
            *reinterpret_cast<float4*>(&Ws[r][c * 4]) =
                *reinterpret_cast<const float4*>(&W[(size_t)(kt + r) * 64 + c * 4]);
        }
        __syncthreads();
        #pragma unroll
        for (int k = 0; k < 32; ++k) {
            const float4 bv = *reinterpret_cast<const float4*>(&Ws[k][tc * 4]);
            float a0 = hs[tn * 4 + 0][k];
            float a1 = hs[tn * 4 + 1][k];
            float a2 = hs[tn * 4 + 2][k];
            float a3 = hs[tn * 4 + 3][k];
            acc[0][0] += a0 * bv.x; acc[0][1] += a0 * bv.y; acc[0][2] += a0 * bv.z; acc[0][3] += a0 * bv.w;
            acc[1][0] += a1 * bv.x; acc[1][1] += a1 * bv.y; acc[1][2] += a1 * bv.z; acc[1][3] += a1 * bv.w;
            acc[2][0] += a2 * bv.x; acc[2][1] += a2 * bv.y; acc[2][2] += a2 * bv.z; acc[2][3] += a2 * bv.w;
            acc[3][0] += a3 * bv.x; acc[3][1] += a3 * bv.y; acc[3][2] += a3 * bv.z; acc[3][3] += a3 * bv.w;
        }
    }

    const int head = tc >> 2;
    #pragma unroll
    for (int i = 0; i < 4; ++i) {
        int n = n0 + tn * 4 + i;
        if (n < NN) {
            ushort4 v;
            v.x = f2bf(acc[i][0]);
            v.y = f2bf(acc[i][1]);
            v.z = f2bf(acc[i][2]);
            v.w = f2bf(acc[i][3]);
            *reinterpret_cast<ushort4*>(&hw[(size_t)n * 64 + tc * 4]) = v;
        }
        float vs = 0.f, vd = 0.f;
        #pragma unroll
        for (int j = 0; j < 4; ++j) {
            int c = (tc * 4 + j) & 15;
            vs += acc[i][j] * asrc[head * 16 + c];
            vd += acc[i][j] * adst[head * 16 + c];
        }
        vs += __shfl_xor(vs, 1); vs += __shfl_xor(vs, 2);
        vd += __shfl_xor(vd, 1); vd += __shfl_xor(vd, 2);
        if ((tc & 3) == 0 && n < NN) {
            as_[n * 4 + head] = vs;
            ad_[n * 4 + head] = vd;
        }
    }
}

// ---------------- fused softmax + aggregation (LDS-staged p, s) ----------------
__global__ __launch_bounds__(256) void k_aggregate(
    const unsigned short* __restrict__ hw, // [NN,64] bf16
    const float* __restrict__ as_,     // [NN,4]
    const float* __restrict__ ad_,     // [NN,4]
    const int* __restrict__ rowptr,
    const int* __restrict__ csr_src,
    const float* __restrict__ bias,    // [64]
    unsigned short* __restrict__ outA) // [NN,64] bf16
{
    __shared__ float pls[4][DCAP][4];
    __shared__ int   sls[4][DCAP];
    const int wv = threadIdx.x >> 6;
    int wave = (blockIdx.x * blockDim.x + threadIdx.x) >> 6;
    int lane = threadIdx.x & 63;
    if (wave >= NN) return;
    const int n = wave;
    const int beg = rowptr[n], end = rowptr[n + 1];
    const int deg = end - beg;
    const int h1 = lane & 3;
    const int slot = lane >> 4;  // unused placeholder (kept minimal diff below)
    const int sl = lane >> 2;
    const float adn1 = ad_[(unsigned)n * 4u + (unsigned)h1];

    // ---- phase 1: online (m,l); stash e and src ----
    float m = -1e30f, l = 0.f;
    for (int j = sl; j < deg; j += 16) {
        int s = csr_src[beg + j];
        float e = as_[(unsigned)s * 4u + (unsigned)h1] + adn1;
        e = (e > 0.f) ? e : NEG * e;
        if (j < DCAP) {
            if (h1 == 0) sls[wv][j] = s;
            pls[wv][j][h1] = e;
        }
        float mn = fmaxf(m, e);
        l = l * __expf(m - mn) + __expf(e - mn);
        m = mn;
    }
    #pragma unroll
    for (int off = 4; off < 64; off <<= 1) {
        float m2 = __shfl_xor(m, off);
        float l2 = __shfl_xor(l, off);
        float mn = fmaxf(m, m2);
        l = l * __expf(m - mn) + l2 * __expf(m2 - mn);
        m = mn;
    }
    const float inv_l = 1.f / (l + 1e-16f);

    // ---- phase 2: normalize p in LDS ----
    const int dcap = (deg < DCAP) ? deg : DCAP;
    for (int j = sl; j < dcap; j += 16)
        pls[wv][j][h1] = __expf(pls[wv][j][h1] - m) * inv_l;

    // ---- phase 3: weighted gather, 8 in flight, 32-bit offsets ----
    const int h2 = lane >> 4;
    const float mh2 = __shfl(m, h2);
    const float il2 = __shfl(inv_l, h2);
    float acc = 0.f;
    int i = 0;
    for (; i + 8 <= dcap; i += 8) {
        unsigned o[8]; float p[8], v[8];
        #pragma unroll
        for (int jj = 0; jj < 8; ++jj) {
            o[jj] = ((unsigned)sls[wv][i + jj] << 6) | (unsigned)lane;
            p[jj] = pls[wv][i + jj][h2];
        }
        #pragma unroll
        for (int jj = 0; jj < 8; ++jj) v[jj] = bf2f(hw[o[jj]]);
        #pragma unroll
        for (int jj = 0; jj < 8; ++jj) acc += p[jj] * v[jj];
    }
    for (; i < dcap; ++i) {
        unsigned o = ((unsigned)sls[wv][i] << 6) | (unsigned)lane;
        acc += pls[wv][i][h2] * bf2f(hw[o]);
    }
    if (deg > DCAP) {
        const float adn2 = ad_[(unsigned)n * 4u + (unsigned)h2];
        for (; i < deg; ++i) {
            int s = csr_src[beg + i];
            float e = as_[(unsigned)s * 4u + (unsigned)h2] + adn2;
            e = (e > 0.f) ? e : NEG * e;
            acc += __expf(e - mh2) * il2 * bf2f(hw[((unsigned)s << 6) | (unsigned)lane]);
        }
    }
    float o = acc + bias[lane];
    outA[((unsigned)n << 6) | (unsigned)lane] = f2bf((o > 0.f) ? o : 0.f);
}

// ---------------- global max pool (batch sorted, h >= 0) ----------------
__global__ void k_pool(const unsigned short* __restrict__ h, const int* __restrict__ batch,
                       unsigned int* __restrict__ g) {
    int wave = (blockIdx.x * blockDim.x + threadIdx.x) >> 6;
    int lane = threadIdx.x & 63;
    int n0 = wave * 32;
    if (n0 >= NN) return;
    int n1 = n0 + 32; if (n1 > NN) n1 = NN;
    int cg = batch[n0];
    float m = 0.f;
    for (int n = n0; n < n1; ++n) {
        int gi = batch[n];
        if (gi != cg) {
            atomicMax(&g[cg * 64 + lane], __float_as_uint(m));
            m = 0.f; cg = gi;
        }
        m = fmaxf(m, bf2f(h[((unsigned)n << 6) | (unsigned)lane]));
    }
    atomicMax(&g[cg * 64 + lane], __float_as_uint(m));
}

// ---------------- MLP head ----------------
__global__ void k_head(const unsigned int* __restrict__ gbits,
                       const float* __restrict__ W1, const float* __restrict__ b1,
                       const float* __restrict__ W2, const float* __restrict__ b2,
                       float* __restrict__ out) {
    __shared__ float gs[NG * 64];
    __shared__ float z1[NG * 32];
    int t = threadIdx.x;
    for (int i = t; i < NG * 64; i += 256) gs[i] = __uint_as_float(gbits[i]);
    __syncthreads();
    for (int i = t; i < NG * 32; i += 256) {
        int gi = i >> 5, c = i & 31;
        float acc = b1[c];
        for (int k = 0; k < 64; ++k) acc += gs[gi * 64 + k] * W1[k * 32 + c];
        z1[i] = (acc > 0.f) ? acc : 0.f;
    }
    __syncthreads();
    for (int i = t; i < NG * 10; i += 256) {
        int gi = i / 10, c = i % 10;
        float acc = b2[c];
        for (int k = 0; k < 32; ++k) acc += z1[gi * 32 + k] * W2[k * 10 + c];
        out[i] = acc;
    }
}

// ---------------- launch ----------------
extern "C" void kernel_launch(void* const* d_in, const int* in_sizes, int n_in,
                              void* d_out, int out_size, void* d_ws, size_t ws_size,
                              hipStream_t stream) {
    const float* x       = (const float*)d_in[0];
    const int*   ei      = (const int*)d_in[1];
    const int*   batch   = (const int*)d_in[2];
    const float* W_in    = (const float*)d_in[3];
    const float* asrc_in = (const float*)d_in[4];
    const float* adst_in = (const float*)d_in[5];
    const float* b_in    = (const float*)d_in[6];
    const float* W_hid   = (const float*)d_in[7];
    const float* asrc_h  = (const float*)d_in[8];
    const float* adst_h  = (const float*)d_in[9];
    const float* b_hid   = (const float*)d_in[10];
    const float* W1      = (const float*)d_in[11];
    const float* b1      = (const float*)d_in[12];
    const float* W2      = (const float*)d_in[13];
    const float* b2      = (const float*)d_in[14];
    float* out = (float*)d_out;

    char* base = (char*)d_ws;
    size_t off = 0;
    auto alloc = [&](size_t bytes) -> char* {
        char* p = base + off;
        off += (bytes + 255) & ~size_t(255);
        return p;
    };
    unsigned short* A  = (unsigned short*)alloc((size_t)NN * 64 * 2);  // bf16 activations
    unsigned short* Bf = (unsigned short*)alloc((size_t)NN * 64 * 2);  // bf16 hw messages
    float* as_    = (float*)alloc((size_t)NN * 4 * 4);
    float* ad_    = (float*)alloc((size_t)NN * 4 * 4);
    int*   counts = (int*)alloc((size_t)NN * 4);
    int*   rowptr = (int*)alloc((size_t)(NN + 1) * 4);
    int*   cursor = (int*)alloc((size_t)(NN + 1) * 4);
    int*   bsums  = (int*)alloc((size_t)NB_SCAN * 4);
    int*   boffs  = (int*)alloc((size_t)NB_SCAN * 4);
    int*   csr    = (int*)alloc((size_t)ET * 4);
    unsigned int* g = (unsigned int*)alloc((size_t)NG * 64 * 4);

    hipMemsetAsync(counts, 0, (size_t)NN * 4, stream);
    hipMemsetAsync(g, 0, (size_t)NG * 64 * 4, stream);

    k_hist<<<NPART * PBLK, 256, 0, stream>>>(ei, counts);
    k_scan_blocks<<<NB_SCAN, 256, 0, stream>>>(counts, rowptr, bsums);
    k_scan_partials<<<1, 64, 0, stream>>>(bsums, boffs);
    k_add_offsets<<<NB_SCAN, 1024, 0, stream>>>(rowptr, boffs, cursor);
    k_scatter<<<NPART * PBLK, 256, 0, stream>>>(ei, cursor, csr);

    const int gemm_blocks = (NN + 63) / 64;             // 1563
    const int node_blocks = (NN * 64 + 255) / 256;      // one wave per node

    // input layer: F=128, f32 input
    k_gemm_alpha<128, false><<<gemm_blocks, 256, 0, stream>>>(x, W_in, asrc_in, adst_in, Bf, as_, ad_);
    k_aggregate<<<node_blocks, 256, 0, stream>>>(Bf, as_, ad_, rowptr, csr, b_in, A);

    // hidden layers: F=64, bf16 input
    for (int i = 0; i < NLAYERS; ++i) {
        k_gemm_alpha<64, true><<<gemm_blocks, 256, 0, stream>>>(
            A, W_hid + (size_t)i * 64 * 64, asrc_h + (size_t)i * 64, adst_h + (size_t)i * 64,
            Bf, as_, ad_);
        k_aggregate<<<node_blocks, 256, 0, stream>>>(Bf, as_, ad_, rowptr, csr, b_hid + (size_t)i * 64, A);
    }

    int pool_waves = (NN + 31) / 32;
    int pool_blocks = (pool_waves * 64 + 255) / 256;
    k_pool<<<pool_blocks, 256, 0, stream>>>(A, batch, g);
    k_head<<<1, 256, 0, stream>>>(g, W1, b1, W2, b2, out);
}

// Round 10
// 788.082 us; speedup vs baseline: 1.7526x; 1.0030x over previous
//
#include <hip/hip_runtime.h>
#include <hip/hip_bf16.h>

// ---------------- problem constants ----------------
#define NN 100000      // nodes
#define NE 1600000     // edges (before self-loops)
#define ET 1700000     // edges + self-loops
#define NG 64          // graphs
#define F_IN 128
#define HID 64         // 4 heads * 16
#define NLAYERS 6      // hidden GAT layers (plus input layer)
#define NEG 0.2f
#define NB_SCAN ((NN + 1023) / 1024)   // 98
#define NPART 8        // dst partitions (XCD heuristic)
#define PBLK 128       // blocks per partition
#define PNN (NN / NPART)   // 12500
#define DCAP 64        // per-wave LDS edge capacity (deg ~ Poisson(16)+1)

static __device__ __forceinline__ unsigned short f2bf(float f) {
    __hip_bfloat16 b = __float2bfloat16(f);
    return *reinterpret_cast<unsigned short*>(&b);
}
static __device__ __forceinline__ float bf2f(unsigned short u) {
    __hip_bfloat16 b = *reinterpret_cast<__hip_bfloat16*>(&u);
    return __bfloat162float(b);
}

// ---------------- CSR build (dst-partitioned for XCD L2 locality) ----------------
__global__ __launch_bounds__(256) void k_hist(const int* __restrict__ ei,
                                              int* __restrict__ counts) {
    const int part = blockIdx.x & (NPART - 1);
    const int sub  = blockIdx.x >> 3;
    const int lo = part * PNN, hi = lo + PNN;
    for (int e = sub * 256 + threadIdx.x; e < ET; e += PBLK * 256) {
        int dst = (e < NE) ? ei[NE + e] : (e - NE);
        if (dst >= lo && dst < hi) atomicAdd(&counts[dst], 1);
    }
}

__global__ void k_scan_blocks(const int* __restrict__ counts,
                              int* __restrict__ excl, int* __restrict__ bsums) {
    __shared__ int sh[256];
    int b = blockIdx.x, t = threadIdx.x;
    int base = b * 1024 + t * 4;
    int c[4];
    #pragma unroll
    for (int j = 0; j < 4; ++j) {
        int idx = base + j;
        c[j] = (idx < NN) ? counts[idx] : 0;
    }
    int s = c[0] + c[1] + c[2] + c[3];
    sh[t] = s;
    __syncthreads();
    for (int off = 1; off < 256; off <<= 1) {
        int v = (t >= off) ? sh[t - off] : 0;
        __syncthreads();
        sh[t] += v;
        __syncthreads();
    }
    int run = sh[t] - s;
    #pragma unroll
    for (int j = 0; j < 4; ++j) {
        int idx = base + j;
        if (idx < NN) excl[idx] = run;
        run += c[j];
    }
    if (t == 255) bsums[b] = sh[t];
}

__global__ void k_scan_partials(const int* __restrict__ bsums, int* __restrict__ boffs) {
    if (threadIdx.x == 0 && blockIdx.x == 0) {
        int run = 0;
        for (int i = 0; i < NB_SCAN; ++i) { boffs[i] = run; run += bsums[i]; }
    }
}

__global__ void k_add_offsets(int* __restrict__ rowptr, const int* __restrict__ boffs,
                              int* __restrict__ cursor) {
    int idx = blockIdx.x * blockDim.x + threadIdx.x;
    if (idx < NN) {
        int v = rowptr[idx] + boffs[blockIdx.x];
        rowptr[idx] = v;
        cursor[idx] = v;
    }
    if (idx == 0) rowptr[NN] = ET;
}

__global__ __launch_bounds__(256) void k_scatter(const int* __restrict__ ei,
                                                 int* __restrict__ cursor,
                                                 int* __restrict__ csr_src) {
    const int part = blockIdx.x & (NPART - 1);
    const int sub  = blockIdx.x >> 3;
    const int lo = part * PNN, hi = lo + PNN;
    for (int e = sub * 256 + threadIdx.x; e < ET; e += PBLK * 256) {
        int dst = (e < NE) ? ei[NE + e] : (e - NE);
        if (dst >= lo && dst < hi) {
            int src = (e < NE) ? ei[e] : dst;
            int pos = atomicAdd(&cursor[dst], 1);
            csr_src[pos] = src;
        }
    }
}

// ---------------- GEMM (h @ W) fused with alpha reductions ----------------
// Tile 64 nodes x 64 cols, K-chunk 32, 4x4 micro-tile.
template<int F, bool BIN>
__global__ __launch_bounds__(256) void k_gemm_alpha(
    const void* __restrict__ hin_,   // [NN, F] f32 or bf16
    const float* __restrict__ W,     // [F, 64]
    const float* __restrict__ asrc,  // [4,16]
    const float* __restrict__ adst,  // [4,16]
    unsigned short* __restrict__ hw, // [NN, 64] bf16
    float* __restrict__ as_,         // [NN, 4]
    float* __restrict__ ad_)         // [NN, 4]
{
    __shared__ float hs[64][36];     // [node][k], K-chunk 32 + pad
    __shared__ float Ws[32][64];     // [k][col]
    const int t = threadIdx.x;
    const int n0 = blockIdx.x * 64;
    const int tc = t & 15;
    const int tn = t >> 4;

    float acc[4][4] = {};

    for (int kt = 0; kt < F; kt += 32) {
        __syncthreads();
        #pragma unroll
        for (int u = 0; u < 2; ++u) {
            int idx = t + u * 256;
            int row = idx >> 3, q = idx & 7;
            int gn = n0 + row;
            if constexpr (BIN) {
                const unsigned short* hb = (const unsigned short*)hin_;
                ushort4 uv = (gn < NN)
                    ? *reinterpret_cast<const ushort4*>(&hb[(size_t)gn * F + kt + q * 4])
                    : make_ushort4(0, 0, 0, 0);
                hs[row][q * 4 + 0] = bf2f(uv.x);
                hs[row][q * 4 + 1] = bf2f(uv.y);
                hs[row][q * 4 + 2] = bf2f(uv.z);
                hs[row][q * 4 + 3] = bf2f(uv.w);
            } else {
                const float* hf = (const float*)hin_;
                float4 v = (gn < NN)
                    ? *reinterpret_cast<const float4*>(&hf[(size_t)gn * F + kt + q * 4])
                    : make_float4(0.f, 0.f, 0.f, 0.f);
                hs[row][q * 4 + 0] = v.x;
                hs[row][q * 4 + 1] = v.y;
                hs[row][q * 4 + 2] = v.z;
                hs[row][q * 4 + 3] = v.w;
            }
        }
        #pragma unroll
        for (int u = 0; u < 2; ++u) {
            int idx = t + u * 256;
            int r = idx >> 4, c = idx & 15;
            *reinterpret_cast<float4*>(&Ws[r][c * 4]) =
                *reinterpret_cast<const float4*>(&W[(size_t)(kt + r) * 64 + c * 4]);
        }
        __syncthreads();
        #pragma unroll
        for (int k = 0; k < 32; ++k) {
            const float4 bv = *reinterpret_cast<const float4*>(&Ws[k][tc * 4]);
            float a0 = hs[tn * 4 + 0][k];
            float a1 = hs[tn * 4 + 1][k];
            float a2 = hs[tn * 4 + 2][k];
            float a3 = hs[tn * 4 + 3][k];
            acc[0][0] += a0 * bv.x; acc[0][1] += a0 * bv.y; acc[0][2] += a0 * bv.z; acc[0][3] += a0 * bv.w;
            acc[1][0] += a1 * bv.x; acc[1][1] += a1 * bv.y; acc[1][2] += a1 * bv.z; acc[1][3] += a1 * bv.w;
            acc[2][0] += a2 * bv.x; acc[2][1] += a2 * bv.y; acc[2][2] += a2 * bv.z; acc[2][3] += a2 * bv.w;
            acc[3][0] += a3 * bv.x; acc[3][1] += a3 * bv.y; acc[3][2] += a3 * bv.z; acc[3][3] += a3 * bv.w;
        }
    }

    const int head = tc >> 2;
    #pragma unroll
    for (int i = 0; i < 4; ++i) {
        int n = n0 + tn * 4 + i;
        if (n < NN) {
            ushort4 v;
            v.x = f2bf(acc[i][0]);
            v.y = f2bf(acc[i][1]);
            v.z = f2bf(acc[i][2]);
            v.w = f2bf(acc[i][3]);
            *reinterpret_cast<ushort4*>(&hw[(size_t)n * 64 + tc * 4]) = v;
        }
        float vs = 0.f, vd = 0.f;
        #pragma unroll
        for (int j = 0; j < 4; ++j) {
            int c = (tc * 4 + j) & 15;
            vs += acc[i][j] * asrc[head * 16 + c];
            vd += acc[i][j] * adst[head * 16 + c];
        }
        vs += __shfl_xor(vs, 1); vs += __shfl_xor(vs, 2);
        vd += __shfl_xor(vd, 1); vd += __shfl_xor(vd, 2);
        if ((tc & 3) == 0 && n < NN) {
            as_[n * 4 + head] = vs;
            ad_[n * 4 + head] = vd;
        }
    }
}

// ---------------- fused softmax + aggregation ----------------
// Fast path (deg <= DCAP, ~always): max-then-exp with deferred normalization:
//   pass A: stash e, fmax only. per-head shfl-max.
//   pass B: p = exp(e-m) (the ONLY exp), l += p, stash p unnormalized.
//   phase 3: acc += p*hv; out = acc * inv_l + bias.
// Slow path (deg > DCAP): R9-proven online (m,l) re-read code.
__global__ __launch_bounds__(256) void k_aggregate(
    const unsigned short* __restrict__ hw, // [NN,64] bf16
    const float* __restrict__ as_,     // [NN,4]
    const float* __restrict__ ad_,     // [NN,4]
    const int* __restrict__ rowptr,
    const int* __restrict__ csr_src,
    const float* __restrict__ bias,    // [64]
    unsigned short* __restrict__ outA) // [NN,64] bf16
{
    __shared__ float pls[4][DCAP][4];
    __shared__ int   sls[4][DCAP];
    const int wv = threadIdx.x >> 6;
    int wave = (blockIdx.x * blockDim.x + threadIdx.x) >> 6;
    int lane = threadIdx.x & 63;
    if (wave >= NN) return;
    const int n = wave;
    const int beg = rowptr[n], end = rowptr[n + 1];
    const int deg = end - beg;
    const int h1 = lane & 3;
    const int sl = lane >> 2;
    const int h2 = lane >> 4;
    const float adn1 = ad_[(unsigned)n * 4u + (unsigned)h1];

    if (deg <= DCAP) {
        // ---- pass A: load, lrelu, stash e, running max ----
        float m = -1e30f;
        for (int j = sl; j < deg; j += 16) {
            int s = csr_src[beg + j];
            float e = as_[(unsigned)s * 4u + (unsigned)h1] + adn1;
            e = (e > 0.f) ? e : NEG * e;
            if (h1 == 0) sls[wv][j] = s;
            pls[wv][j][h1] = e;
            m = fmaxf(m, e);
        }
        #pragma unroll
        for (int off = 4; off < 64; off <<= 1)
            m = fmaxf(m, __shfl_xor(m, off));

        // ---- pass B: single exp, accumulate l, stash unnormalized p ----
        float l = 0.f;
        for (int j = sl; j < deg; j += 16) {
            float p = __expf(pls[wv][j][h1] - m);
            pls[wv][j][h1] = p;
            l += p;
        }
        #pragma unroll
        for (int off = 4; off < 64; off <<= 1)
            l += __shfl_xor(l, off);
        const float inv_l = 1.f / (l + 1e-16f);
        const float il2 = __shfl(inv_l, h2);   // lane h2 has head h2's value

        // ---- phase 3: weighted gather, 8 in flight ----
        float acc = 0.f;
        int i = 0;
        for (; i + 8 <= deg; i += 8) {
            unsigned o[8]; float p[8], v[8];
            #pragma unroll
            for (int jj = 0; jj < 8; ++jj) {
                o[jj] = ((unsigned)sls[wv][i + jj] << 6) | (unsigned)lane;
                p[jj] = pls[wv][i + jj][h2];
            }
            #pragma unroll
            for (int jj = 0; jj < 8; ++jj) v[jj] = bf2f(hw[o[jj]]);
            #pragma unroll
            for (int jj = 0; jj < 8; ++jj) acc += p[jj] * v[jj];
        }
        for (; i < deg; ++i) {
            unsigned o = ((unsigned)sls[wv][i] << 6) | (unsigned)lane;
            acc += pls[wv][i][h2] * bf2f(hw[o]);
        }
        float o = acc * il2 + bias[lane];
        outA[((unsigned)n << 6) | (unsigned)lane] = f2bf((o > 0.f) ? o : 0.f);
    } else {
        // ---- slow path: proven online (m,l) + re-read (deg > DCAP: ~never) ----
        float m = -1e30f, l = 0.f;
        for (int j = sl; j < deg; j += 16) {
            int s = csr_src[beg + j];
            float e = as_[(unsigned)s * 4u + (unsigned)h1] + adn1;
            e = (e > 0.f) ? e : NEG * e;
            float mn = fmaxf(m, e);
            l = l * __expf(m - mn) + __expf(e - mn);
            m = mn;
        }
        #pragma unroll
        for (int off = 4; off < 64; off <<= 1) {
            float m2 = __shfl_xor(m, off);
            float l2 = __shfl_xor(l, off);
            float mn = fmaxf(m, m2);
            l = l * __expf(m - mn) + l2 * __expf(m2 - mn);
            m = mn;
        }
        const float inv_l = 1.f / (l + 1e-16f);
        const float mh2 = __shfl(m, h2);
        const float il2 = __shfl(inv_l, h2);
        const float adn2 = ad_[(unsigned)n * 4u + (unsigned)h2];
        float acc = 0.f;
        for (int i = 0; i < deg; ++i) {
            int s = csr_src[beg + i];
            float e = as_[(unsigned)s * 4u + (unsigned)h2] + adn2;
            e = (e > 0.f) ? e : NEG * e;
            acc += __expf(e - mh2) * bf2f(hw[((unsigned)s << 6) | (unsigned)lane]);
        }
        float o = acc * il2 + bias[lane];
        outA[((unsigned)n << 6) | (unsigned)lane] = f2bf((o > 0.f) ? o : 0.f);
    }
}

// ---------------- global max pool (batch sorted, h >= 0) ----------------
__global__ void k_pool(const unsigned short* __restrict__ h, const int* __restrict__ batch,
                       unsigned int* __restrict__ g) {
    int wave = (blockIdx.x * blockDim.x + threadIdx.x) >> 6;
    int lane = threadIdx.x & 63;
    int n0 = wave * 32;
    if (n0 >= NN) return;
    int n1 = n0 + 32; if (n1 > NN) n1 = NN;
    int cg = batch[n0];
    float m = 0.f;
    for (int n = n0; n < n1; ++n) {
        int gi = batch[n];
        if (gi != cg) {
            atomicMax(&g[cg * 64 + lane], __float_as_uint(m));
            m = 0.f; cg = gi;
        }
        m = fmaxf(m, bf2f(h[((unsigned)n << 6) | (unsigned)lane]));
    }
    atomicMax(&g[cg * 64 + lane], __float_as_uint(m));
}

// ---------------- MLP head ----------------
__global__ void k_head(const unsigned int* __restrict__ gbits,
                       const float* __restrict__ W1, const float* __restrict__ b1,
                       const float* __restrict__ W2, const float* __restrict__ b2,
                       float* __restrict__ out) {
    __shared__ float gs[NG * 64];
    __shared__ float z1[NG * 32];
    int t = threadIdx.x;
    for (int i = t; i < NG * 64; i += 256) gs[i] = __uint_as_float(gbits[i]);
    __syncthreads();
    for (int i = t; i < NG * 32; i += 256) {
        int gi = i >> 5, c = i & 31;
        float acc = b1[c];
        for (int k = 0; k < 64; ++k) acc += gs[gi * 64 + k] * W1[k * 32 + c];
        z1[i] = (acc > 0.f) ? acc : 0.f;
    }
    __syncthreads();
    for (int i = t; i < NG * 10; i += 256) {
        int gi = i / 10, c = i % 10;
        float acc = b2[c];
        for (int k = 0; k < 32; ++k) acc += z1[gi * 32 + k] * W2[k * 10 + c];
        out[i] = acc;
    }
}

// ---------------- launch ----------------
extern "C" void kernel_launch(void* const* d_in, const int* in_sizes, int n_in,
                              void* d_out, int out_size, void* d_ws, size_t ws_size,
                              hipStream_t stream) {
    const float* x       = (const float*)d_in[0];
    const int*   ei      = (const int*)d_in[1];
    const int*   batch   = (const int*)d_in[2];
    const float* W_in    = (const float*)d_in[3];
    const float* asrc_in = (const float*)d_in[4];
    const float* adst_in = (const float*)d_in[5];
    const float* b_in    = (const float*)d_in[6];
    const float* W_hid   = (const float*)d_in[7];
    const float* asrc_h  = (const float*)d_in[8];
    const float* adst_h  = (const float*)d_in[9];
    const float* b_hid   = (const float*)d_in[10];
    const float* W1      = (const float*)d_in[11];
    const float* b1      = (const float*)d_in[12];
    const float* W2      = (const float*)d_in[13];
    const float* b2      = (const float*)d_in[14];
    float* out = (float*)d_out;

    char* base = (char*)d_ws;
    size_t off = 0;
    auto alloc = [&](size_t bytes) -> char* {
        char* p = base + off;
        off += (bytes + 255) & ~size_t(255);
        return p;
    };
    unsigned short* A  = (unsigned short*)alloc((size_t)NN * 64 * 2);  // bf16 activations
    unsigned short* Bf = (unsigned short*)alloc((size_t)NN * 64 * 2);  // bf16 hw messages
    float* as_    = (float*)alloc((size_t)NN * 4 * 4);
    float* ad_    = (float*)alloc((size_t)NN * 4 * 4);
    int*   counts = (int*)alloc((size_t)NN * 4);
    int*   rowptr = (int*)alloc((size_t)(NN + 1) * 4);
    int*   cursor = (int*)alloc((size_t)(NN + 1) * 4);
    int*   bsums  = (int*)alloc((size_t)NB_SCAN * 4);
    int*   boffs  = (int*)alloc((size_t)NB_SCAN * 4);
    int*   csr    = (int*)alloc((size_t)ET * 4);
    unsigned int* g = (unsigned int*)alloc((size_t)NG * 64 * 4);

    hipMemsetAsync(counts, 0, (size_t)NN * 4, stream);
    hipMemsetAsync(g, 0, (size_t)NG * 64 * 4, stream);

    k_hist<<<NPART * PBLK, 256, 0, stream>>>(ei, counts);
    k_scan_blocks<<<NB_SCAN, 256, 0, stream>>>(counts, rowptr, bsums);
    k_scan_partials<<<1, 64, 0, stream>>>(bsums, boffs);
    k_add_offsets<<<NB_SCAN, 1024, 0, stream>>>(rowptr, boffs, cursor);
    k_scatter<<<NPART * PBLK, 256, 0, stream>>>(ei, cursor, csr);

    const int gemm_blocks = (NN + 63) / 64;
    const int node_blocks = (NN * 64 + 255) / 256;

    // input layer: F=128, f32 input
    k_gemm_alpha<128, false><<<gemm_blocks, 256, 0, stream>>>(x, W_in, asrc_in, adst_in, Bf, as_, ad_);
    k_aggregate<<<node_blocks, 256, 0, stream>>>(Bf, as_, ad_, rowptr, csr, b_in, A);

    // hidden layers: F=64, bf16 input
    for (int i = 0; i < NLAYERS; ++i) {
        k_gemm_alpha<64, true><<<gemm_blocks, 256, 0, stream>>>(
            A, W_hid + (size_t)i * 64 * 64, asrc_h + (size_t)i * 64, adst_h + (size_t)i * 64,
            Bf, as_, ad_);
        k_aggregate<<<node_blocks, 256, 0, stream>>>(Bf, as_, ad_, rowptr, csr, b_hid + (size_t)i * 64, A);
    }

    int pool_waves = (NN + 31) / 32;
    int pool_blocks = (pool_waves * 64 + 255) / 256;
    k_pool<<<pool_blocks, 256, 0, stream>>>(A, batch, g);
    k_head<<<1, 256, 0, stream>>>(g, W1, b1, W2, b2, out);
}